// Round 1
// baseline (8545.029 us; speedup 1.0000x reference)
//
#include <hip/hip_runtime.h>
#include <math.h>

#define B_    1000
#define N_    20
#define D_    172
#define DE_   172
#define DT_   100
#define E_    272
#define DK_   444
#define HD_   136
#define INV_SQRT_HD 0.08574929257125442f

// ---------------------------------------------------------------------------
// Batched transpose: src[l][r][c] -> dst[l][c][r]
// ---------------------------------------------------------------------------
__global__ void transpose_batched(const float* __restrict__ src, float* __restrict__ dst,
                                  int rows, int cols) {
    int idx = blockIdx.x * blockDim.x + threadIdx.x;
    int tot = 2 * rows * cols;
    if (idx >= tot) return;
    int l = idx / (rows * cols);
    int rem = idx - l * rows * cols;
    int r = rem / cols, c = rem - r * cols;
    dst[(size_t)l * rows * cols + (size_t)c * rows + r] = src[idx];
}

// ---------------------------------------------------------------------------
// Fused TGN temporal-attention layer. One block per query.
// LAYER 0: Bq = 20000 (1-hop neighbors aggregated from 2-hop), out -> emb1
// LAYER 1: Bq = 1000  (source aggregated from 1-hop),          out -> d_out
// Weight pointers are passed already offset to layer l, transposed so that
// W*T[i*OUT + e] = W[e][i]  (coalesced over e = threadIdx).
// ---------------------------------------------------------------------------
template<int LAYER>
__global__ __launch_bounds__(320)
void aggregate_kernel(
    const float* __restrict__ memory,
    const float* __restrict__ edge_features,
    const int*   __restrict__ source_nodes,
    const float* __restrict__ timestamps,
    const int*   __restrict__ neighbors1,
    const int*   __restrict__ edge_idxs1,
    const float* __restrict__ edge_times1,
    const int*   __restrict__ neighbors2,
    const int*   __restrict__ edge_idxs2,
    const float* __restrict__ edge_times2,
    const float* __restrict__ w_time,
    const float* __restrict__ b_time,
    const float* __restrict__ WqT, const float* __restrict__ bq,
    const float* __restrict__ WkT, const float* __restrict__ bk,
    const float* __restrict__ WvT, const float* __restrict__ bv,
    const float* __restrict__ WoT, const float* __restrict__ bo,
    const float* __restrict__ W1T, const float* __restrict__ b1,
    const float* __restrict__ W2T, const float* __restrict__ b2,
    const float* __restrict__ emb1_in,
    float* __restrict__ outp)
{
    __shared__ float kvT[DK_][N_];   // kv rows, transposed: kvT[i][n]
    __shared__ float sf[D_];         // source features
    __shared__ float xq[E_];         // [src || st_emb]; later reused as o[]
    __shared__ float qv[E_];         // q
    __shared__ float kq[E_][N_];     // k[n][e]*q[e] partials for score reduce
    __shared__ float sc[2][N_];      // scores
    __shared__ float aw[2][N_];      // softmax weights
    __shared__ int   msk[N_];
    __shared__ int   allm;
    __shared__ float x1[DK_];        // [o' || src] MLP input
    __shared__ float h1[D_];         // relu hidden

    const int g = blockIdx.x;
    const int t = threadIdx.x;
    const int b = (LAYER == 0) ? (g / N_) : g;
    const float ts = timestamps[b];

    int src_node;
    const int*   nbrs;
    const int*   eidx;
    const float* etim;
    if (LAYER == 0) {
        src_node = neighbors1[g];                 // src1 = memory[neighbors1.flat]
        nbrs = neighbors2  + (size_t)g * N_;
        eidx = edge_idxs2  + (size_t)g * N_;
        etim = edge_times2 + (size_t)g * N_;
    } else {
        src_node = source_nodes[b];
        nbrs = neighbors1  + (size_t)b * N_;
        eidx = edge_idxs1  + (size_t)b * N_;
        etim = edge_times1 + (size_t)b * N_;
    }

    // ---- build kvT = [neigh_emb || time_enc(dt) || edge_feat]^T in LDS ----
    for (int n = 0; n < N_; ++n) {
        const int   nb = nbrs[n];
        const int   ei = eidx[n];
        const float dt = ts - etim[n];
        if (t == 0) msk[n] = (nb == 0);
        if (LAYER == 0) {
            const float* mrow = memory + (size_t)nb * D_;
            for (int i = t; i < D_; i += 320) kvT[i][n] = mrow[i];
        } else {
            const float* mrow = emb1_in + ((size_t)b * N_ + n) * D_;
            for (int i = t; i < D_; i += 320) kvT[i][n] = mrow[i];
        }
        for (int j = t; j < DT_; j += 320)
            kvT[D_ + j][n] = cosf(dt * w_time[j] + b_time[j]);
        const float* erow = edge_features + (size_t)ei * DE_;
        for (int i = t; i < DE_; i += 320) kvT[D_ + DT_ + i][n] = erow[i];
    }
    // ---- source features and query input [src || cos(b_time)] ----
    {
        const float* srow = memory + (size_t)src_node * D_;
        for (int i = t; i < D_; i += 320) { float v = srow[i]; sf[i] = v; xq[i] = v; }
        for (int j = t; j < DT_; j += 320) xq[D_ + j] = cosf(b_time[j]);  // t=0 enc
    }
    __syncthreads();

    // ---- q = xq @ Wq^T + bq ----
    if (t < E_) {
        float acc = bq[t];
        for (int i = 0; i < E_; ++i) acc += xq[i] * WqT[i * E_ + t];
        qv[t] = acc;
    }
    __syncthreads();

    // ---- dominant dual GEMM: column t of k and v over 20 rows ----
    float accK[N_], accV[N_];
    if (t < E_) {
        #pragma unroll
        for (int r = 0; r < N_; ++r) { accK[r] = 0.f; accV[r] = 0.f; }
        for (int i = 0; i < DK_; ++i) {
            const float wk = WkT[i * E_ + t];
            const float wv = WvT[i * E_ + t];
            const float4* row = (const float4*)&kvT[i][0];  // 80B rows, 16B aligned
            #pragma unroll
            for (int r4 = 0; r4 < N_ / 4; ++r4) {
                const float4 x = row[r4];
                accK[4*r4+0] += x.x * wk;  accV[4*r4+0] += x.x * wv;
                accK[4*r4+1] += x.y * wk;  accV[4*r4+1] += x.y * wv;
                accK[4*r4+2] += x.z * wk;  accV[4*r4+2] += x.z * wv;
                accK[4*r4+3] += x.w * wk;  accV[4*r4+3] += x.w * wv;
            }
        }
        const float qe  = qv[t];
        const float bke = bk[t];
        #pragma unroll
        for (int r = 0; r < N_; ++r) kq[t][r] = (accK[r] + bke) * qe;
    }
    __syncthreads();

    // ---- scores: reduce kq over each head's 136 columns ----
    if (t < 2 * N_) {
        const int h = t / N_, n = t - (t / N_) * N_;
        float s = 0.f;
        for (int e = 0; e < HD_; ++e) s += kq[h * HD_ + e][n];
        s *= INV_SQRT_HD;
        if (msk[n]) s = -1e9f;
        sc[h][n] = s;
    }
    if (t == 0) {
        int am = 1;
        #pragma unroll
        for (int n = 0; n < N_; ++n) am &= msk[n];
        allm = am;
    }
    __syncthreads();

    // ---- softmax over 20 neighbors, per head ----
    if (t < 2) {
        float m = -INFINITY;
        #pragma unroll
        for (int n = 0; n < N_; ++n) m = fmaxf(m, sc[t][n]);
        float ex[N_], ssum = 0.f;
        #pragma unroll
        for (int n = 0; n < N_; ++n) { ex[n] = expf(sc[t][n] - m); ssum += ex[n]; }
        const float inv = 1.f / ssum;
        #pragma unroll
        for (int n = 0; n < N_; ++n) aw[t][n] = ex[n] * inv;
    }
    __syncthreads();

    // ---- o[e] = sum_n a[h][n] * v[n][e]  (+ bv since sum(a)=1) ----
    if (t < E_) {
        const int h = t / HD_;
        float oe = 0.f;
        #pragma unroll
        for (int n = 0; n < N_; ++n) oe += aw[h][n] * accV[n];
        xq[t] = oe + bv[t];           // reuse xq as o[]
    }
    __syncthreads();

    // ---- o' = o @ Wo^T + bo; zero if fully masked; build MLP input ----
    if (t < E_) {
        float acc = bo[t];
        for (int i = 0; i < E_; ++i) acc += xq[i] * WoT[i * E_ + t];
        x1[t] = allm ? 0.f : acc;
    }
    if (t < D_) x1[E_ + t] = sf[t];
    __syncthreads();

    // ---- MLP: h = relu([o'||src] @ W1^T + b1); out = h @ W2^T + b2 ----
    if (t < D_) {
        float acc = b1[t];
        for (int i = 0; i < DK_; ++i) acc += x1[i] * W1T[i * D_ + t];
        h1[t] = fmaxf(acc, 0.f);
    }
    __syncthreads();
    if (t < D_) {
        float acc = b2[t];
        for (int i = 0; i < D_; ++i) acc += h1[i] * W2T[i * D_ + t];
        outp[(size_t)g * D_ + t] = acc;
    }
}

// ---------------------------------------------------------------------------
extern "C" void kernel_launch(void* const* d_in, const int* in_sizes, int n_in,
                              void* d_out, int out_size, void* d_ws, size_t ws_size,
                              hipStream_t stream) {
    const float* memory        = (const float*)d_in[0];
    const float* edge_features = (const float*)d_in[1];
    const int*   source_nodes  = (const int*)  d_in[2];
    const float* timestamps    = (const float*)d_in[3];
    const int*   neighbors1    = (const int*)  d_in[4];
    const int*   edge_idxs1    = (const int*)  d_in[5];
    const float* edge_times1   = (const float*)d_in[6];
    const int*   neighbors2    = (const int*)  d_in[7];
    const int*   edge_idxs2    = (const int*)  d_in[8];
    const float* edge_times2   = (const float*)d_in[9];
    const float* w_time        = (const float*)d_in[10];
    const float* b_time        = (const float*)d_in[11];
    const float* Wq = (const float*)d_in[12];
    const float* bq = (const float*)d_in[13];
    const float* Wk = (const float*)d_in[14];
    const float* bk = (const float*)d_in[15];
    const float* Wv = (const float*)d_in[16];
    const float* bv = (const float*)d_in[17];
    const float* Wo = (const float*)d_in[18];
    const float* bo = (const float*)d_in[19];
    const float* W1 = (const float*)d_in[20];
    const float* b1 = (const float*)d_in[21];
    const float* W2 = (const float*)d_in[22];
    const float* b2 = (const float*)d_in[23];

    float* ws = (float*)d_ws;
    size_t off = 0;
    float* WqT = ws + off; off += (size_t)2 * E_  * E_;
    float* WkT = ws + off; off += (size_t)2 * DK_ * E_;
    float* WvT = ws + off; off += (size_t)2 * DK_ * E_;
    float* WoT = ws + off; off += (size_t)2 * E_  * E_;
    float* W1T = ws + off; off += (size_t)2 * DK_ * D_;
    float* W2T = ws + off; off += (size_t)2 * D_  * D_;
    float* emb1 = ws + off; off += (size_t)(B_ * N_) * D_;   // 20000 x 172

    auto tp = [&](const float* src, float* dst, int rows, int cols) {
        int tot = 2 * rows * cols;
        transpose_batched<<<(tot + 255) / 256, 256, 0, stream>>>(src, dst, rows, cols);
    };
    tp(Wq, WqT, E_, E_);
    tp(Wk, WkT, E_, DK_);
    tp(Wv, WvT, E_, DK_);
    tp(Wo, WoT, E_, E_);
    tp(W1, W1T, D_, DK_);
    tp(W2, W2T, D_, D_);

    // Layer 1 (l=0): 20000 queries -> emb1
    aggregate_kernel<0><<<B_ * N_, 320, 0, stream>>>(
        memory, edge_features, source_nodes, timestamps,
        neighbors1, edge_idxs1, edge_times1,
        neighbors2, edge_idxs2, edge_times2,
        w_time, b_time,
        WqT, bq, WkT, bk, WvT, bv, WoT, bo, W1T, b1, W2T, b2,
        nullptr, emb1);

    // Layer 2 (l=1): 1000 queries -> d_out
    aggregate_kernel<1><<<B_, 320, 0, stream>>>(
        memory, edge_features, source_nodes, timestamps,
        neighbors1, edge_idxs1, edge_times1,
        neighbors2, edge_idxs2, edge_times2,
        w_time, b_time,
        WqT + E_ * E_,  bq + E_,
        WkT + DK_ * E_, bk + E_,
        WvT + DK_ * E_, bv + E_,
        WoT + E_ * E_,  bo + E_,
        W1T + DK_ * D_, b1 + D_,
        W2T + D_ * D_,  b2 + D_,
        emb1, (float*)d_out);
}